// Round 10
// baseline (233.378 us; speedup 1.0000x reference)
//
#include <hip/hip_runtime.h>
#include <math.h>

#define NBINS 182
#define NB 128   // batch

typedef unsigned short u16;
typedef __attribute__((ext_vector_type(8))) short short8;   // 8 bf16 (4 VGPRs)
typedef __attribute__((ext_vector_type(4))) float f32x4;    // MFMA accumulator

__device__ __forceinline__ u16 f2bf(float f) {
    union { float f; unsigned u; } v; v.f = f;
    unsigned r = v.u + 0x7FFF + ((v.u >> 16) & 1);   // RNE
    return (u16)(r >> 16);
}
__device__ __forceinline__ float bf2f(u16 u) {
    union { unsigned u; float f; } v; v.u = ((unsigned)u) << 16;
    return v.f;
}
__device__ __forceinline__ short8 negbf(short8 v) {
    short8 r;
#pragma unroll
    for (int i = 0; i < 8; ++i) r[i] = v[i] ^ (short)0x8000;
    return r;
}

__device__ __forceinline__ int radial_bin(int dx, int dy) {
    int d2 = dx * dx + dy * dy;
    int bin = (int)sqrtf((float)d2);
    while ((bin + 1) * (bin + 1) <= d2) ++bin;
    while (bin * bin > d2) --bin;
    return bin;
}

#define MFMA __builtin_amdgcn_mfma_f32_16x16x32_bf16

// ---------------------------------------------------------------------------
// prep (round-6 verified form, verbatim): one launch, 4 jobs by block range.
//   [0,256)      build_M row j (fp64 accum -> M fp32 + A1 bf16)
//   [256,512)    nr partial histogram -> nrpart[row][bin]
//   [512,544)    zero tbin + Tt_im row 128 (bitwise +0)
//   [544,1568)   gray grid-stride: G = luma(x) bf16
// ---------------------------------------------------------------------------
__global__ __launch_bounds__(256) void prep(const float* __restrict__ x,
                                            u16* __restrict__ G,
                                            float* __restrict__ M_re,
                                            float* __restrict__ M_im,
                                            u16* __restrict__ A1,
                                            float* __restrict__ nrpart,
                                            float* __restrict__ tbin,
                                            u16* __restrict__ Tt_im) {
    __shared__ double ctab[1024];
    __shared__ double stab[1024];
    __shared__ float s[NBINS];
    int blk = blockIdx.x;
    int t = threadIdx.x;

    if (blk < 256) {             // ---- build_M ----
        for (int i = t; i < 1024; i += 256) {
            double a = 3.14159265358979323846 * (double)i / 512.0;
            ctab[i] = cos(a);
            stab[i] = sin(a);
        }
        __syncthreads();
        int j = blk;
        int w = t;
        double re = 0.0, im = 0.0;
        int tw = 2 * w + 1;
        for (int k = 0; k < 256; ++k) {
            int e = (4 * j * k) & 1023;
            int m = (tw * k) & 1023;
            double cw = 2.0 * ctab[m];
            re += ctab[e] * cw;
            im -= stab[e] * cw;
        }
        M_re[j * 256 + w] = (float)re;
        M_im[j * 256 + w] = (float)im;
        A1[j * 256 + w] = f2bf((float)re);
        A1[(j + 256) * 256 + w] = f2bf((float)im);
    } else if (blk < 512) {      // ---- nr partial histogram, row i ----
        int i = blk - 256;
        if (t < NBINS) s[t] = 0.0f;
        __syncthreads();
        int bin = radial_bin(t - 128, i - 128);
        atomicAdd(&s[bin], 1.0f);
        __syncthreads();
        if (t < NBINS) nrpart[i * NBINS + t] = s[t];
    } else if (blk < 544) {      // ---- zero tbin + Tt_im row 128 ----
        int idx = (blk - 512) * 256 + t;
        for (int i = idx; i < NB * NBINS; i += 32 * 256) tbin[i] = 0.0f;
        for (int i = idx; i < NB * 128; i += 32 * 256) {
            int bb = i >> 7, off = (i & 127) << 1;
            *(unsigned*)(Tt_im + (size_t)bb * 65536 + 128 * 256 + off) = 0u;
        }
    } else {                     // ---- gray, grid-stride ----
        int tid = (blk - 544) * 256 + t;          // 0..262143
        for (int i = tid; i < 2097152; i += 262144) {   // 8 iters
            int idx = i * 4;
            int b = idx >> 16;
            int rem = idx & 65535;
            const float* p = x + (size_t)b * 196608 + rem;
            float4 r = *(const float4*)p;
            float4 g = *(const float4*)(p + 65536);
            float4 bl = *(const float4*)(p + 131072);
            float g0 = 0.2989f * r.x + 0.587f * g.x + 0.114f * bl.x;
            float g1 = 0.2989f * r.y + 0.587f * g.y + 0.114f * bl.y;
            float g2 = 0.2989f * r.z + 0.587f * g.z + 0.114f * bl.z;
            float g3 = 0.2989f * r.w + 0.587f * g.w + 0.114f * bl.w;
            uint2 o;
            o.x = (unsigned)f2bf(g0) | ((unsigned)f2bf(g1) << 16);
            o.y = (unsigned)f2bf(g2) | ((unsigned)f2bf(g3) << 16);
            *(uint2*)(G + idx) = o;
        }
    }
}

// ---------------------------------------------------------------------------
// Stage 1, DIRECT-READ form (BISECT step 2; rounds-7/8 phase-1 with GLOBAL
// stores): Tt[r][h] = sum_w A1[r,w] * G[b,h,w].
// Grid (4,1,NB) x 512 thr (8 waves), LDS=0, no barriers.
// Block (b,q): Tt rows [32q,32q+32) re+im.  Wave wv: tau=wv&3 selects
// (re0,re1,im0,im1) 16-row tile, hh=wv>>2 the h-half (tiles j=8hh..8hh+7).
// Operand bits == round-6 staged s1 (same A1/G values, same ascending-kk
// chain, one MFMA per tile per kk) -> bit-identical Tt.
// q==0 also replays re row 128 (A rows 128+fr, tiles j=2wv,2wv+1, keep
// fragment row 0) == round-6 y==2 chains bit-exactly.
// ---------------------------------------------------------------------------
__global__ __launch_bounds__(512) void s1(const u16* __restrict__ A1,
                                          const u16* __restrict__ G,
                                          u16* __restrict__ Tt_re,
                                          u16* __restrict__ Tt_im) {
    int b = blockIdx.z;
    int q = blockIdx.x;                 // 0..3
    int t = threadIdx.x;
    int lane = t & 63, wv = t >> 6;     // 8 waves
    int fr = lane & 15;
    int fk = (lane >> 4) << 3;
    int rq = (lane >> 4) << 2;
    int tau = wv & 3, hh = wv >> 2;
    int arow = (tau < 2) ? (32 * q + 16 * tau) : (256 + 32 * q + 16 * (tau - 2));

    const u16* Af = A1 + (size_t)(arow + fr) * 256;
    const u16* A28 = A1 + (size_t)(128 + fr) * 256;
    const u16* Gb = G + (size_t)b * 65536;

    f32x4 acc[8], a128[2];
#pragma unroll
    for (int j = 0; j < 8; ++j) acc[j] = (f32x4){0.f, 0.f, 0.f, 0.f};
    a128[0] = (f32x4){0.f, 0.f, 0.f, 0.f};
    a128[1] = (f32x4){0.f, 0.f, 0.f, 0.f};

    for (int kk = 0; kk < 256; kk += 32) {
        short8 afr = *(const short8*)(Af + kk + fk);
        short8 a28f = *(const short8*)(A28 + kk + fk);
#pragma unroll
        for (int j2 = 0; j2 < 8; ++j2) {
            int j = 8 * hh + j2;
            short8 bf = *(const short8*)(Gb + (size_t)(16 * j + fr) * 256 + kk + fk);
            acc[j2] = MFMA(afr, bf, acc[j2], 0, 0, 0);
            if (q == 0 && (j >> 1) == wv)
                a128[j & 1] = MFMA(a28f, bf, a128[j & 1], 0, 0, 0);
        }
    }

    u16* dst = ((tau < 2) ? Tt_re : Tt_im) + (size_t)b * 65536;
    int orow = 32 * q + 16 * (tau & 1);
#pragma unroll
    for (int j2 = 0; j2 < 8; ++j2) {
        int col = 16 * (8 * hh + j2) + fr;
#pragma unroll
        for (int reg = 0; reg < 4; ++reg)
            dst[(size_t)(orow + rq + reg) * 256 + col] = f2bf(acc[j2][reg]);
    }
    if (q == 0 && (lane >> 4) == 0) {   // fragment row 0 == Tt row 128 (reg 0)
        size_t base = (size_t)b * 65536 + 128 * 256;
        Tt_re[base + 32 * wv + lane] = f2bf(a128[0][0]);
        Tt_re[base + 32 * wv + 16 + lane] = f2bf(a128[1][0]);
    }
}

// ---------------------------------------------------------------------------
// s2f (round-6 verified form, verbatim): paired-column GEMM, 640 blocks.
// [0,512): GEMM, b=blk>>2, u0=((blk>>1)&1)*64, j0=(blk&1)*64, v in [j0,j0+64).
// [512,640): row128 (F[128,j] via fp32 dots).
// ---------------------------------------------------------------------------
__global__ __launch_bounds__(256) void s2f(const u16* __restrict__ A1,
                                           const float* __restrict__ M_re,
                                           const u16* __restrict__ Tt_re,
                                           const u16* __restrict__ Tt_im,
                                           float* __restrict__ tbin) {
    __shared__ u16 Ar[64 * 40], Ai[64 * 40], Br[64 * 40], Bi[64 * 40];
    __shared__ u16 Br3[16 * 40], Bi3[16 * 40];
    __shared__ float sbins[NBINS];
    __shared__ float sM[256];
    int blk = blockIdx.x;
    int t = threadIdx.x;

    if (blk >= 512) {            // ---- row128 ----
        int b = blk - 512;
        sM[t] = M_re[128 * 256 + t];
        __syncthreads();
        if (t > 128) return;
        const u16* pr = Tt_re + (size_t)b * 65536 + (size_t)t * 256;
        const u16* pi = Tt_im + (size_t)b * 65536 + (size_t)t * 256;
        float re = 0.0f, im = 0.0f;
        for (int h = 0; h < 256; h += 8) {
            uint4 vr = *(const uint4*)(pr + h);
            uint4 vi = *(const uint4*)(pi + h);
            unsigned wr[4] = {vr.x, vr.y, vr.z, vr.w};
            unsigned wi[4] = {vi.x, vi.y, vi.z, vi.w};
#pragma unroll
            for (int q = 0; q < 4; ++q) {
                re = fmaf(sM[h + 2 * q], bf2f((u16)(wr[q] & 0xffff)), re);
                re = fmaf(sM[h + 2 * q + 1], bf2f((u16)(wr[q] >> 16)), re);
                im = fmaf(sM[h + 2 * q], bf2f((u16)(wi[q] & 0xffff)), im);
                im = fmaf(sM[h + 2 * q + 1], bf2f((u16)(wi[q] >> 16)), im);
            }
        }
        re += 1e-8f; im += 1e-8f;
        float mag = logf(sqrtf(re * re + im * im + 1e-10f) + 1e-10f);
        float wj = (t == 0 || t == 128) ? 1.0f : 2.0f;
        int dx = (t < 128) ? t : t - 256;
        int bin = radial_bin(dx, -128);
        atomicAdd(&tbin[b * NBINS + bin], wj * mag);
        return;
    }

    // ---- paired GEMM ----
    int b = blk >> 2;
    int u0 = ((blk >> 1) & 1) * 64;
    int j0 = (blk & 1) * 64;                 // v in [j0, j0+64), all < 128
    int lane = t & 63, wv = t >> 6;
    int wu = (wv >> 1) * 32;
    int wj = (wv & 1) * 32;
    int fr = lane & 15;
    int fk = (lane >> 4) << 3;
    bool do128 = (j0 == 64) && ((wv & 1) == 0);   // col-128 replay waves

    for (int i = t; i < NBINS; i += 256) sbins[i] = 0.0f;

    f32x4 accr1[2][2], acci1[2][2], accr2[2][2], acci2[2][2];
    f32x4 acc3r[2], acc3i[2];
#pragma unroll
    for (int i = 0; i < 2; ++i) {
#pragma unroll
        for (int j = 0; j < 2; ++j) {
            accr1[i][j] = (f32x4){0.f, 0.f, 0.f, 0.f};
            acci1[i][j] = (f32x4){0.f, 0.f, 0.f, 0.f};
            accr2[i][j] = (f32x4){0.f, 0.f, 0.f, 0.f};
            acci2[i][j] = (f32x4){0.f, 0.f, 0.f, 0.f};
        }
        acc3r[i] = (f32x4){0.f, 0.f, 0.f, 0.f};
        acc3i[i] = (f32x4){0.f, 0.f, 0.f, 0.f};
    }

    const u16* Apr = A1 + (size_t)u0 * 256;
    const u16* Api = A1 + (size_t)(256 + u0) * 256;

    int lrow = t >> 2, loff = (t & 3) << 3;
    const u16* Trs = Tt_re + (size_t)b * 65536 + (size_t)(j0 + lrow) * 256;
    const u16* Tis = Tt_im + (size_t)b * 65536 + (size_t)(j0 + lrow) * 256;
    // col-128 replay staging source (rows 128..143; rows >128 only feed
    // discarded columns): threads 0..63 -> Br3, 64..127 -> Bi3
    int r3 = (t & 63) >> 2, o3 = (t & 3) << 3;
    const u16* T3s = (((t >> 6) == 0) ? Tt_re : Tt_im)
                   + (size_t)b * 65536 + (size_t)(128 + r3) * 256;

    for (int kk = 0; kk < 256; kk += 32) {
        *(uint4*)&Ar[lrow * 40 + loff] =
            *(const uint4*)(Apr + (size_t)lrow * 256 + kk + loff);
        *(uint4*)&Ai[lrow * 40 + loff] =
            *(const uint4*)(Api + (size_t)lrow * 256 + kk + loff);
        *(uint4*)&Br[lrow * 40 + loff] = *(const uint4*)(Trs + kk + loff);
        *(uint4*)&Bi[lrow * 40 + loff] = *(const uint4*)(Tis + kk + loff);
        if (j0 == 64 && t < 128) {
            uint4 v3 = *(const uint4*)(T3s + kk + o3);
            if (t < 64) *(uint4*)&Br3[r3 * 40 + o3] = v3;
            else        *(uint4*)&Bi3[r3 * 40 + o3] = v3;
        }
        __syncthreads();
        short8 arf[2], aif[2], naif[2], brf[2], bif[2], nbif[2];
#pragma unroll
        for (int i = 0; i < 2; ++i) {
            arf[i] = *(const short8*)&Ar[(wu + i * 16 + fr) * 40 + fk];
            aif[i] = *(const short8*)&Ai[(wu + i * 16 + fr) * 40 + fk];
            naif[i] = negbf(aif[i]);
        }
#pragma unroll
        for (int j = 0; j < 2; ++j) {
            brf[j] = *(const short8*)&Br[(wj + j * 16 + fr) * 40 + fk];
            bif[j] = *(const short8*)&Bi[(wj + j * 16 + fr) * 40 + fk];
            nbif[j] = negbf(bif[j]);
        }
#pragma unroll
        for (int i = 0; i < 2; ++i)
#pragma unroll
            for (int j = 0; j < 2; ++j) {
                accr1[i][j] = MFMA(arf[i], brf[j], accr1[i][j], 0, 0, 0);
                accr1[i][j] = MFMA(naif[i], bif[j], accr1[i][j], 0, 0, 0);
                acci1[i][j] = MFMA(arf[i], bif[j], acci1[i][j], 0, 0, 0);
                acci1[i][j] = MFMA(aif[i], brf[j], acci1[i][j], 0, 0, 0);
                accr2[i][j] = MFMA(arf[i], brf[j], accr2[i][j], 0, 0, 0);
                accr2[i][j] = MFMA(aif[i], bif[j], accr2[i][j], 0, 0, 0);
                acci2[i][j] = MFMA(arf[i], nbif[j], acci2[i][j], 0, 0, 0);
                acci2[i][j] = MFMA(aif[i], brf[j], acci2[i][j], 0, 0, 0);
            }
        if (do128) {
            short8 brf3 = *(const short8*)&Br3[fr * 40 + fk];
            short8 bif3 = *(const short8*)&Bi3[fr * 40 + fk];
#pragma unroll
            for (int i = 0; i < 2; ++i) {
                acc3r[i] = MFMA(arf[i], brf3, acc3r[i], 0, 0, 0);
                acc3r[i] = MFMA(naif[i], bif3, acc3r[i], 0, 0, 0);
                acc3i[i] = MFMA(arf[i], bif3, acc3i[i], 0, 0, 0);
                acc3i[i] = MFMA(aif[i], brf3, acc3i[i], 0, 0, 0);
            }
        }
        __syncthreads();
    }

    int rq = (lane >> 4) << 2;
#pragma unroll
    for (int i = 0; i < 2; ++i)
#pragma unroll
        for (int j = 0; j < 2; ++j) {
            int v = j0 + wj + j * 16 + fr;            // 0..127, dx = v
#pragma unroll
            for (int reg = 0; reg < 4; ++reg) {
                int u = u0 + wu + i * 16 + rq + reg;  // 0..127
                float wrow = (u == 0) ? 1.0f : 2.0f;
                float re1 = accr1[i][j][reg] + 1e-8f;
                float im1 = acci1[i][j][reg] + 1e-8f;
                float m1 = logf(sqrtf(re1 * re1 + im1 * im1 + 1e-10f) + 1e-10f);
                float val;
                if (v == 0) {
                    val = wrow * m1;                  // column 256-v doesn't exist
                } else {
                    float re2 = accr2[i][j][reg] + 1e-8f;
                    float im2 = acci2[i][j][reg] + 1e-8f;
                    float m2 = logf(sqrtf(re2 * re2 + im2 * im2 + 1e-10f) + 1e-10f);
                    val = wrow * (m1 + m2);           // same bin: dx^2 equal
                }
                int bin = radial_bin(v, u);
                atomicAdd(&sbins[bin], val);
            }
        }
    if (do128 && fr == 0) {      // col-128 replay epilogue (kept column only)
#pragma unroll
        for (int i = 0; i < 2; ++i)
#pragma unroll
            for (int reg = 0; reg < 4; ++reg) {
                int u = u0 + wu + i * 16 + rq + reg;
                float wrow = (u == 0) ? 1.0f : 2.0f;
                float re = acc3r[i][reg] + 1e-8f;
                float im = acc3i[i][reg] + 1e-8f;
                float mag = logf(sqrtf(re * re + im * im + 1e-10f) + 1e-10f);
                int bin = radial_bin(-128, u);
                atomicAdd(&sbins[bin], wrow * mag);
            }
    }
    __syncthreads();
    for (int i = t; i < NBINS; i += 256)
        atomicAdd(&tbin[b * NBINS + i], sbins[i]);
}

// ---------------------------------------------------------------------------
// Finalize (round-6 verbatim): nr = column-sum of nrpart; prof = tbin/nr;
// min-max over 1..179; dot bins 90..179 with w.
// ---------------------------------------------------------------------------
__global__ __launch_bounds__(192) void finalize(const float* __restrict__ tbin,
                                                const float* __restrict__ nrpart,
                                                const float* __restrict__ w,
                                                const float* __restrict__ bias,
                                                float* __restrict__ out) {
    __shared__ float prof[NBINS];
    __shared__ float smn, smx, ssum;
    int b = blockIdx.x;
    int t = threadIdx.x;
    if (t < NBINS) {
        float nr = 0.0f;
        for (int i = 0; i < 256; ++i) nr += nrpart[i * NBINS + t];
        prof[t] = tbin[b * NBINS + t] / (nr + 1e-10f);
    }
    __syncthreads();
    if (t == 0) {
        float mn = prof[1], mx = prof[1];
        for (int i = 2; i <= 179; ++i) {
            float p = prof[i];
            mn = fminf(mn, p);
            mx = fmaxf(mx, p);
        }
        smn = mn; smx = mx; ssum = 0.0f;
    }
    __syncthreads();
    if (t < 90) {
        float denom = smx - smn;
        float v = (prof[90 + t] - smn) / denom;
        if (v != v) v = 0.0f;
        atomicAdd(&ssum, v * w[t]);
    }
    __syncthreads();
    if (t == 0) out[b] = ssum + bias[0];
}

// ---------------------------------------------------------------------------
extern "C" void kernel_launch(void* const* d_in, const int* in_sizes, int n_in,
                              void* d_out, int out_size, void* d_ws, size_t ws_size,
                              hipStream_t stream) {
    const float* x = (const float*)d_in[0];     // (128,3,256,256)
    const float* w = (const float*)d_in[1];     // (1,90)
    const float* bias = (const float*)d_in[2];  // (1,)
    float* out = (float*)d_out;                 // (128,1)

    float* M_re = (float*)d_ws;                    // 65536 f
    float* M_im = M_re + 65536;                    // 65536 f
    u16* A1 = (u16*)(M_im + 65536);                // 512*256 u16
    u16* G = A1 + 131072;                          // 128*65536 u16
    u16* Tt_re = G + (size_t)NB * 65536;           // 128*65536 u16 (rows 0..128 used)
    u16* Tt_im = Tt_re + (size_t)NB * 65536;       // 128*65536 u16 (rows 0..128 used)
    float* tbin = (float*)(Tt_im + (size_t)NB * 65536);   // NB*NBINS f
    float* nrpart = tbin + NB * NBINS;             // 256*NBINS f

    prep<<<1568, 256, 0, stream>>>(x, G, M_re, M_im, A1, nrpart, tbin, Tt_im);
    s1<<<dim3(4, 1, NB), 512, 0, stream>>>(A1, G, Tt_re, Tt_im);
    s2f<<<640, 256, 0, stream>>>(A1, M_re, Tt_re, Tt_im, tbin);
    finalize<<<NB, 192, 0, stream>>>(tbin, nrpart, w, bias, out);
}